// Round 1
// 516.959 us; speedup vs baseline: 1.0648x; 1.0648x over previous
//
#include <hip/hip_runtime.h>
#include <hip/hip_bf16.h>

#define C_ 256
#define H_ 256
#define V_ 10000
#define N_ 8
#define T_ 256
#define TM1_ 255
#define NB_ ((V_ + 31) / 32)   // 313 col-tiles for the term head
#define SW_ 8                  // waves per scan block

typedef _Float16 h2_t __attribute__((ext_vector_type(2)));
typedef _Float16 h4_t __attribute__((ext_vector_type(4)));
typedef _Float16 h8_t __attribute__((ext_vector_type(8)));
typedef float f4v __attribute__((ext_vector_type(4)));

// barrier with LDS-only drain (global loads/stores stay in flight)
__device__ __forceinline__ void bar_lgkm() {
  asm volatile("s_waitcnt lgkmcnt(0)\ns_barrier" ::: "memory");
}

// ---- wave64 reductions via DPP (answer broadcast from lane 63) ----
__device__ __forceinline__ float wave_red_max(float v) {
#define DPP_MAX(ctrl) { int iv_ = __float_as_int(v); \
  int r_ = __builtin_amdgcn_update_dpp(iv_, iv_, ctrl, 0xF, 0xF, false); \
  v = fmaxf(v, __int_as_float(r_)); }
  DPP_MAX(0x111) DPP_MAX(0x112) DPP_MAX(0x114) DPP_MAX(0x118)
  DPP_MAX(0x142) DPP_MAX(0x143)
#undef DPP_MAX
  return __int_as_float(__builtin_amdgcn_readlane(__float_as_int(v), 63));
}
__device__ __forceinline__ float wave_red_sum(float v) {
#define DPP_ADD(ctrl) { \
  int r_ = __builtin_amdgcn_update_dpp(0, __float_as_int(v), ctrl, 0xF, 0xF, true); \
  v += __int_as_float(r_); }
  DPP_ADD(0x111) DPP_ADD(0x112) DPP_ADD(0x114) DPP_ADD(0x118)
  DPP_ADD(0x142) DPP_ADD(0x143)
#undef DPP_ADD
  return __int_as_float(__builtin_amdgcn_readlane(__float_as_int(v), 63));
}

__device__ __forceinline__ float block_allmax(float v, float* red) {
  v = wave_red_max(v);
  if ((threadIdx.x & 63) == 0) red[threadIdx.x >> 6] = v;
  __syncthreads();
  v = fmaxf(fmaxf(red[0], red[1]), fmaxf(red[2], red[3]));
  __syncthreads();
  return v;
}
__device__ __forceinline__ float block_allsum(float v, float* red) {
  v = wave_red_sum(v);
  if ((threadIdx.x & 63) == 0) red[threadIdx.x >> 6] = v;
  __syncthreads();
  v = (red[0] + red[1]) + (red[2] + red[3]);
  __syncthreads();
  return v;
}

// ---- residual MLP body: 4 rows per block, 256 threads ----
__device__ __forceinline__ void mlp4(
    const float* __restrict__ emb,
    const float* __restrict__ w1, const float* __restrict__ b1,
    const float* __restrict__ w2, const float* __restrict__ b2,
    int r0, float (&e_s)[4][C_], float (&h_s)[4][C_], float (&h2_s)[4][C_]) {
  const int tid = threadIdx.x;
#pragma unroll
  for (int rr = 0; rr < 4; ++rr)
    e_s[rr][tid] = emb[(r0 + rr) * H_ + tid];
  __syncthreads();
  float bb = b1[tid];
  float a0 = bb, a1 = bb, a2 = bb, a3 = bb;
  for (int k4 = 0; k4 < H_ / 4; ++k4) {
    float4 e0 = ((const float4*)e_s[0])[k4];
    float4 e1 = ((const float4*)e_s[1])[k4];
    float4 e2 = ((const float4*)e_s[2])[k4];
    float4 e3 = ((const float4*)e_s[3])[k4];
    const float* wp = w1 + (k4 * 4) * H_ + tid;
    float wa = wp[0], wb = wp[H_], wc = wp[2 * H_], wd = wp[3 * H_];
    a0 = fmaf(e0.x, wa, a0); a0 = fmaf(e0.y, wb, a0);
    a0 = fmaf(e0.z, wc, a0); a0 = fmaf(e0.w, wd, a0);
    a1 = fmaf(e1.x, wa, a1); a1 = fmaf(e1.y, wb, a1);
    a1 = fmaf(e1.z, wc, a1); a1 = fmaf(e1.w, wd, a1);
    a2 = fmaf(e2.x, wa, a2); a2 = fmaf(e2.y, wb, a2);
    a2 = fmaf(e2.z, wc, a2); a2 = fmaf(e2.w, wd, a2);
    a3 = fmaf(e3.x, wa, a3); a3 = fmaf(e3.y, wb, a3);
    a3 = fmaf(e3.z, wc, a3); a3 = fmaf(e3.w, wd, a3);
  }
  h_s[0][tid] = fmaxf(a0, 0.f);
  h_s[1][tid] = fmaxf(a1, 0.f);
  h_s[2][tid] = fmaxf(a2, 0.f);
  h_s[3][tid] = fmaxf(a3, 0.f);
  __syncthreads();
  bb = b2[tid];
  a0 = bb; a1 = bb; a2 = bb; a3 = bb;
  for (int k4 = 0; k4 < H_ / 4; ++k4) {
    float4 e0 = ((const float4*)h_s[0])[k4];
    float4 e1 = ((const float4*)h_s[1])[k4];
    float4 e2 = ((const float4*)h_s[2])[k4];
    float4 e3 = ((const float4*)h_s[3])[k4];
    const float* wp = w2 + (k4 * 4) * H_ + tid;
    float wa = wp[0], wb = wp[H_], wc = wp[2 * H_], wd = wp[3 * H_];
    a0 = fmaf(e0.x, wa, a0); a0 = fmaf(e0.y, wb, a0);
    a0 = fmaf(e0.z, wc, a0); a0 = fmaf(e0.w, wd, a0);
    a1 = fmaf(e1.x, wa, a1); a1 = fmaf(e1.y, wb, a1);
    a1 = fmaf(e1.z, wc, a1); a1 = fmaf(e1.w, wd, a1);
    a2 = fmaf(e2.x, wa, a2); a2 = fmaf(e2.y, wb, a2);
    a2 = fmaf(e2.z, wc, a2); a2 = fmaf(e2.w, wd, a2);
    a3 = fmaf(e3.x, wa, a3); a3 = fmaf(e3.y, wb, a3);
    a3 = fmaf(e3.z, wc, a3); a3 = fmaf(e3.w, wd, a3);
  }
  h2_s[0][tid] = fmaxf(a0, 0.f) + e_s[0][tid];
  h2_s[1][tid] = fmaxf(a1, 0.f) + e_s[1][tid];
  h2_s[2][tid] = fmaxf(a2, 0.f) + e_s[2][tid];
  h2_s[3][tid] = fmaxf(a3, 0.f) + e_s[3][tid];
  __syncthreads();
}

// ---- start MLP -> scalar logit per state ----
__global__ __launch_bounds__(256) void k_start(
    const float* __restrict__ emb, const float* __restrict__ w1,
    const float* __restrict__ b1, const float* __restrict__ w2,
    const float* __restrict__ b2, const float* __restrict__ w3,
    const float* __restrict__ b3, float* __restrict__ slogit) {
  __shared__ __align__(16) float e_s[4][C_], h_s[4][C_], h2_s[4][C_];
  __shared__ float red[4];
  const int r0 = blockIdx.x * 4;
  const int tid = threadIdx.x;
  mlp4(emb, w1, b1, w2, b2, r0, e_s, h_s, h2_s);
  float w3v = w3[tid];
  float s0 = block_allsum(h2_s[0][tid] * w3v, red);
  float s1 = block_allsum(h2_s[1][tid] * w3v, red);
  float s2 = block_allsum(h2_s[2][tid] * w3v, red);
  float s3 = block_allsum(h2_s[3][tid] * w3v, red);
  if (tid == 0) {
    float bb = b3[0];
    slogit[r0 + 0] = s0 + bb;
    slogit[r0 + 1] = s1 + bb;
    slogit[r0 + 2] = s2 + bb;
    slogit[r0 + 3] = s3 + bb;
  }
}

__global__ void k_init(const float* __restrict__ slogit, float* __restrict__ initv) {
  __shared__ float red[4];
  const int tid = threadIdx.x;
  float x = slogit[tid];
  float m = block_allmax(x, red);
  float se = block_allsum(__expf(x - m), red);
  initv[tid] = x - m - __logf(se);
}

// ---- trans MLP -> row-softmax, P / P*logP / P^T (f32 + f16 copies) ----
__global__ __launch_bounds__(256) void k_trans(
    const float* __restrict__ emb, const float* __restrict__ w1,
    const float* __restrict__ b1, const float* __restrict__ w2,
    const float* __restrict__ b2, const float* __restrict__ w3,
    const float* __restrict__ b3, float* __restrict__ Pf,
    float* __restrict__ PLf, float* __restrict__ PTf,
    _Float16* __restrict__ P_h, _Float16* __restrict__ PT_h) {
  __shared__ __align__(16) float e_s[4][C_], h_s[4][C_], h2_s[4][C_];
  __shared__ float red[4];
  const int r0 = blockIdx.x * 4;
  const int tid = threadIdx.x;
  mlp4(emb, w1, b1, w2, b2, r0, e_s, h_s, h2_s);
  float lb = b3[tid];
  float l0 = lb, l1 = lb, l2 = lb, l3 = lb;
  for (int k4 = 0; k4 < H_ / 4; ++k4) {
    float4 e0 = ((const float4*)h2_s[0])[k4];
    float4 e1 = ((const float4*)h2_s[1])[k4];
    float4 e2 = ((const float4*)h2_s[2])[k4];
    float4 e3 = ((const float4*)h2_s[3])[k4];
    const float* wp = w3 + (k4 * 4) * C_ + tid;
    float wa = wp[0], wb = wp[C_], wc = wp[2 * C_], wd = wp[3 * C_];
    l0 = fmaf(e0.x, wa, l0); l0 = fmaf(e0.y, wb, l0);
    l0 = fmaf(e0.z, wc, l0); l0 = fmaf(e0.w, wd, l0);
    l1 = fmaf(e1.x, wa, l1); l1 = fmaf(e1.y, wb, l1);
    l1 = fmaf(e1.z, wc, l1); l1 = fmaf(e1.w, wd, l1);
    l2 = fmaf(e2.x, wa, l2); l2 = fmaf(e2.y, wb, l2);
    l2 = fmaf(e2.z, wc, l2); l2 = fmaf(e2.w, wd, l2);
    l3 = fmaf(e3.x, wa, l3); l3 = fmaf(e3.y, wb, l3);
    l3 = fmaf(e3.z, wc, l3); l3 = fmaf(e3.w, wd, l3);
  }
  float lg[4] = {l0, l1, l2, l3};
#pragma unroll
  for (int rr = 0; rr < 4; ++rr) {
    float m = block_allmax(lg[rr], red);
    float e = __expf(lg[rr] - m);
    float se = block_allsum(e, red);
    float p = e / se;                       // softmax prob
    float tv = lg[rr] - m - __logf(se);     // log-softmax
    const int r = r0 + rr;
    Pf[r * C_ + tid] = p;
    PLf[r * C_ + tid] = p * tv;
    PTf[tid * C_ + r] = p;
    P_h[r * C_ + tid] = (_Float16)p;
    PT_h[tid * C_ + r] = (_Float16)p;
  }
}

// ---- term MLP -> H2 (row-major) and H2T (transposed) ----
__global__ __launch_bounds__(256) void k_term_mlp(
    const float* __restrict__ emb, const float* __restrict__ w1,
    const float* __restrict__ b1, const float* __restrict__ w2,
    const float* __restrict__ b2, float* __restrict__ H2,
    float* __restrict__ H2T) {
  __shared__ __align__(16) float e_s[4][C_], h_s[4][C_], h2_s[4][C_];
  const int r0 = blockIdx.x * 4;
  const int tid = threadIdx.x;
  mlp4(emb, w1, b1, w2, b2, r0, e_s, h_s, h2_s);
#pragma unroll
  for (int rr = 0; rr < 4; ++rr) {
    const int r = r0 + rr;
    float v = h2_s[rr][tid];
    H2[r * H_ + tid] = v;
    H2T[tid * C_ + r] = v;
  }
}

// ---- term head: per-row online logsumexp partials over a 32-col tile ----
__global__ __launch_bounds__(256) void k_term_stats(
    const float* __restrict__ H2, const float* __restrict__ w3,
    const float* __restrict__ b3, float* __restrict__ partm,
    float* __restrict__ parts) {
  __shared__ __align__(16) float w3_s[H_][32];
  __shared__ float b3_s[32];
  const int v0 = blockIdx.x * 32;
  const int tid = threadIdx.x;
  const int ncols = min(32, V_ - v0);
  for (int idx = tid; idx < H_ * 32; idx += 256) {
    int k = idx >> 5, c = idx & 31;
    w3_s[k][c] = (c < ncols) ? w3[k * V_ + v0 + c] : 0.f;
  }
  if (tid < 32) b3_s[tid] = (tid < ncols) ? b3[v0 + tid] : 0.f;
  __syncthreads();
  float acc[32];
#pragma unroll
  for (int c = 0; c < 32; ++c) acc[c] = 0.f;
  const float4* hq = (const float4*)(H2 + tid * H_);
  for (int k4 = 0; k4 < H_ / 4; ++k4) {
    float4 h = hq[k4];
    float hk[4];
    *(float4*)hk = h;
#pragma unroll
    for (int kk = 0; kk < 4; ++kk) {
      float hv = hk[kk];
      const int k = k4 * 4 + kk;
      const float4* wq = (const float4*)(&w3_s[k][0]);
#pragma unroll
      for (int c4 = 0; c4 < 8; ++c4) {
        float4 w = wq[c4];
        acc[c4 * 4 + 0] = fmaf(hv, w.x, acc[c4 * 4 + 0]);
        acc[c4 * 4 + 1] = fmaf(hv, w.y, acc[c4 * 4 + 1]);
        acc[c4 * 4 + 2] = fmaf(hv, w.z, acc[c4 * 4 + 2]);
        acc[c4 * 4 + 3] = fmaf(hv, w.w, acc[c4 * 4 + 3]);
      }
    }
  }
  float m = -1e30f;
#pragma unroll
  for (int c = 0; c < 32; ++c) {
    acc[c] += b3_s[c];
    if (c < ncols) m = fmaxf(m, acc[c]);
  }
  float se = 0.f;
#pragma unroll
  for (int c = 0; c < 32; ++c)
    if (c < ncols) se += __expf(acc[c] - m);
  partm[blockIdx.x * C_ + tid] = m;
  parts[blockIdx.x * C_ + tid] = se;
}

__global__ void k_denom(const float* __restrict__ partm,
                        const float* __restrict__ parts,
                        float* __restrict__ denom) {
  const int r = threadIdx.x;
  float m = -1e30f;
  for (int b = 0; b < NB_; ++b) m = fmaxf(m, partm[b * C_ + r]);
  float s = 0.f;
  for (int b = 0; b < NB_; ++b)
    s += parts[b * C_ + r] * __expf(partm[b * C_ + r] - m);
  denom[r] = m + __logf(s);
}

// ---- emissions: EOBS[nt][c] = exp(obs - K), Karr[nt] = max_c obs ----
__global__ __launch_bounds__(256) void k_obs2(
    const int* __restrict__ text, const float* __restrict__ H2T,
    const float* __restrict__ w3, const float* __restrict__ b3,
    const float* __restrict__ denom, float* __restrict__ EOBS,
    float* __restrict__ Karr) {
  __shared__ __align__(16) float w_s[H_][8];   // [k][i]
  __shared__ float redm[4][8];
  const int c = threadIdx.x;
  const int wid = c >> 6;
  const int lane = c & 63;
  const int base = blockIdx.x * 8;
  int tok[8];
#pragma unroll
  for (int i = 0; i < 8; ++i) tok[i] = text[base + i];
  float wtmp[8];
#pragma unroll
  for (int i = 0; i < 8; ++i) wtmp[i] = w3[c * V_ + tok[i]];
  float b3t[8];
#pragma unroll
  for (int i = 0; i < 8; ++i) b3t[i] = b3[tok[i]];
#pragma unroll
  for (int i = 0; i < 8; ++i) w_s[c][i] = wtmp[i];
  __syncthreads();
  float acc[8];
#pragma unroll
  for (int i = 0; i < 8; ++i) acc[i] = 0.f;
  for (int k4 = 0; k4 < H_ / 4; ++k4) {
    float hv[4];
#pragma unroll
    for (int kk = 0; kk < 4; ++kk) hv[kk] = H2T[(k4 * 4 + kk) * C_ + c];
#pragma unroll
    for (int kk = 0; kk < 4; ++kk) {
      const float4* wq = (const float4*)(&w_s[k4 * 4 + kk][0]);
      float4 wa = wq[0], wb = wq[1];
      acc[0] = fmaf(hv[kk], wa.x, acc[0]);
      acc[1] = fmaf(hv[kk], wa.y, acc[1]);
      acc[2] = fmaf(hv[kk], wa.z, acc[2]);
      acc[3] = fmaf(hv[kk], wa.w, acc[3]);
      acc[4] = fmaf(hv[kk], wb.x, acc[4]);
      acc[5] = fmaf(hv[kk], wb.y, acc[5]);
      acc[6] = fmaf(hv[kk], wb.z, acc[6]);
      acc[7] = fmaf(hv[kk], wb.w, acc[7]);
    }
  }
  float dn = denom[c];
  float obsv[8];
#pragma unroll
  for (int i = 0; i < 8; ++i) obsv[i] = acc[i] + b3t[i] - dn;
#pragma unroll
  for (int i = 0; i < 8; ++i) {
    float wm = wave_red_max(obsv[i]);
    if (lane == 0) redm[wid][i] = wm;
  }
  __syncthreads();
#pragma unroll
  for (int i = 0; i < 8; ++i) {
    float Ki = fmaxf(fmaxf(redm[0][i], redm[1][i]),
                     fmaxf(redm[2][i], redm[3][i]));
    EOBS[(base + i) * C_ + c] = __expf(obsv[i] - Ki);
    if (c == 0) Karr[base + i] = Ki;
  }
}

// ---- MFMA scan v5: same math as k_scan4, restructured for latency hiding ----
// 16 blocks (fwd n=0..7 with P, bwd with P^T), 512 threads = 8 waves.
// Each wave owns 2 output 16-row tiles (vs 4 waves x 4 tiles before):
//  - per-wave issue work halves; 2 waves/SIMD overlap each other's stalls
//  - eo/K prefetch is 2 steps deep (each EOBS slab read is a cold L2 miss;
//    1-step window made the miss latency the per-step floor)
// B-fragment reads stay wave-uniform across nn16 (LDS broadcast, no extra BW).
__global__ __launch_bounds__(512, 2) void k_scan5(
    const _Float16* __restrict__ P_h, const _Float16* __restrict__ PT_h,
    const float* __restrict__ initv, const float* __restrict__ EOBS,
    const float* __restrict__ Karr, float* __restrict__ AL,
    float* __restrict__ BL, float* __restrict__ CC, float* __restrict__ DD,
    float* __restrict__ LOGZ) {
  __shared__ __align__(16) _Float16 ubuf[2][C_];
  __shared__ __align__(16) float red[SW_];
  const int tid = threadIdx.x;
  const int w = tid >> 6;
  const int lane = tid & 63;
  const int quad = lane >> 4;        // k-group within fragment
  const int nn16 = lane & 15;        // replicated column index
  const bool bwd = blockIdx.x >= N_;
  const int n = blockIdx.x & (N_ - 1);
  const _Float16* __restrict__ M = bwd ? PT_h : P_h;

  // A fragments: A[row = w*32 + m*16 + nn16][k = kt*32 + quad*8 + j]
  h8_t afrag[2][8];
#pragma unroll
  for (int m = 0; m < 2; ++m) {
    const _Float16* rp = M + (size_t)((w << 5) + (m << 4) + nn16) * C_ + (quad << 3);
#pragma unroll
    for (int kt = 0; kt < 8; ++kt)
      afrag[m][kt] = *(const h8_t*)(rp + (kt << 5));
  }
  // rows owned by this lane (replicated across nn16): st0(m) = stb + m*16
  const int stb = (w << 5) + (quad << 2);

  if (!bwd) {
    // ---- init: x0 = initv + log(eo0) + K0 ; u0 = exp(x0 - m0) ----
    float K0 = Karr[n * T_];
    f4v x0[2];
    float lmax = -1e30f;
#pragma unroll
    for (int m = 0; m < 2; ++m) {
      const int st0 = stb + (m << 4);
      f4v iv = *(const f4v*)(initv + st0);
      f4v e0 = *(const f4v*)(EOBS + (size_t)(n * T_) * C_ + st0);
#pragma unroll
      for (int r = 0; r < 4; ++r) {
        x0[m][r] = iv[r] + __logf(e0[r]) + K0;
        lmax = fmaxf(lmax, x0[m][r]);
      }
    }
    float wmx = wave_red_max(lmax);
    if (lane == 0) red[w] = wmx;
    __syncthreads();
    f4v rr0 = *(const f4v*)&red[0];
    f4v rr1 = *(const f4v*)&red[4];
    float m0 = fmaxf(fmaxf(fmaxf(rr0[0], rr0[1]), fmaxf(rr0[2], rr0[3])),
                     fmaxf(fmaxf(rr1[0], rr1[1]), fmaxf(rr1[2], rr1[3])));
    __syncthreads();
    float Cacc = m0;
    f4v uval[2];
#pragma unroll
    for (int m = 0; m < 2; ++m) {
      const int st0 = stb + (m << 4);
#pragma unroll
      for (int r = 0; r < 4; ++r) uval[m][r] = __expf(x0[m][r] - m0);
      if (nn16 == 0) {
        h4_t p;
#pragma unroll
        for (int r = 0; r < 4; ++r) p[r] = (_Float16)uval[m][r];
        *(h4_t*)(&ubuf[0][st0]) = p;
        *(f4v*)(AL + (size_t)(0 * N_ + n) * C_ + st0) = uval[m];
      }
    }
    if (tid == 0) CC[0 * N_ + n] = Cacc;
    // 2-deep prefetch pipeline: eo_nx = eo(t+1), eo_p1 = eo(t+2)
    float invm = 1.f, logm = 0.f;
    f4v eo_nx[2], eo_p1[2];
#pragma unroll
    for (int m = 0; m < 2; ++m) {
      eo_nx[m] = *(const f4v*)(EOBS + (size_t)(n * T_ + 1) * C_ + stb + (m << 4));
      eo_p1[m] = *(const f4v*)(EOBS + (size_t)(n * T_ + 2) * C_ + stb + (m << 4));
    }
    float K_nx = Karr[n * T_ + 1];
    float K_p1 = Karr[n * T_ + 2];
    __syncthreads();

#pragma unroll 1
    for (int t = 0; t < TM1_; ++t) {
      const int cur = t & 1, nxt = cur ^ 1;
      f4v eo_p2[2];
      float K_p2 = 0.f;
      if (t + 3 < T_) {
#pragma unroll
        for (int m = 0; m < 2; ++m)
          eo_p2[m] = *(const f4v*)(EOBS + (size_t)(n * T_ + t + 3) * C_ + stb + (m << 4));
        K_p2 = Karr[n * T_ + t + 3];
      }
      // B-frags: broadcast reads, uniform across nn16
      h8_t bf[8];
#pragma unroll
      for (int kt = 0; kt < 8; ++kt)
        bf[kt] = *(const h8_t*)(&ubuf[cur][(kt << 5) + (quad << 3)]);
      f4v acc[2];
      acc[0] = (f4v){0.f, 0.f, 0.f, 0.f};
      acc[1] = (f4v){0.f, 0.f, 0.f, 0.f};
#pragma unroll
      for (int kt = 0; kt < 8; ++kt) {
        acc[0] = __builtin_amdgcn_mfma_f32_16x16x32_f16(afrag[0][kt], bf[kt], acc[0], 0, 0, 0);
        acc[1] = __builtin_amdgcn_mfma_f32_16x16x32_f16(afrag[1][kt], bf[kt], acc[1], 0, 0, 0);
      }
      // epilogue: u = acc * invm * eo
      float lmx = -1e30f;
#pragma unroll
      for (int m = 0; m < 2; ++m) {
#pragma unroll
        for (int r = 0; r < 4; ++r) {
          float u = acc[m][r] * invm * eo_nx[m][r];
          uval[m][r] = u;
          lmx = fmaxf(lmx, u);
        }
      }
      Cacc += K_nx + logm;
      const bool resc = (t & 3) == 3;
      if (resc) {
        float wmm = wave_red_max(lmx);
        if (lane == 0) red[w] = wmm;
      }
      if (nn16 == 0) {
#pragma unroll
        for (int m = 0; m < 2; ++m) {
          const int st0 = stb + (m << 4);
          h4_t p;
#pragma unroll
          for (int r = 0; r < 4; ++r) p[r] = (_Float16)uval[m][r];
          *(h4_t*)(&ubuf[nxt][st0]) = p;
          *(f4v*)(AL + (size_t)((t + 1) * N_ + n) * C_ + st0) = uval[m];
        }
      }
      if (tid == 0) CC[(t + 1) * N_ + n] = Cacc;
      bar_lgkm();
      if (resc) {
        f4v q0 = *(const f4v*)&red[0];
        f4v q1 = *(const f4v*)&red[4];
        float mm = fmaxf(fmaxf(fmaxf(q0[0], q0[1]), fmaxf(q0[2], q0[3])),
                         fmaxf(fmaxf(q1[0], q1[1]), fmaxf(q1[2], q1[3])));
        mm = fmaxf(mm, 1e-30f);
        invm = 1.f / mm;
        logm = __logf(mm);
      } else { invm = 1.f; logm = 0.f; }
#pragma unroll
      for (int m = 0; m < 2; ++m) { eo_nx[m] = eo_p1[m]; eo_p1[m] = eo_p2[m]; }
      K_nx = K_p1; K_p1 = K_p2;
    }
    // logZ = log(sum of last u / 16 replicas) + Cacc
    float s = 0.f;
#pragma unroll
    for (int m = 0; m < 2; ++m)
      s += (uval[m][0] + uval[m][1]) + (uval[m][2] + uval[m][3]);
    s = wave_red_sum(s);
    if (lane == 0) red[w] = s;
    __syncthreads();
    if (tid == 0) {
      float S = ((red[0] + red[1]) + (red[2] + red[3])) +
                ((red[4] + red[5]) + (red[6] + red[7]));
      LOGZ[n] = __logf(S * (1.f / 16.f)) + Cacc;
    }
  } else {
    // ---- bwd: v = bl*eo staged; bl' = (PT*v)*invm ----
    float Dacc = 0.f;
    f4v vval[2];
#pragma unroll
    for (int m = 0; m < 2; ++m) {
      const int st0 = stb + (m << 4);
      vval[m] = *(const f4v*)(EOBS + ((size_t)n * T_ + TM1_) * C_ + st0);
      if (nn16 == 0) {
        h4_t p;
#pragma unroll
        for (int r = 0; r < 4; ++r) p[r] = (_Float16)vval[m][r];
        *(h4_t*)(&ubuf[0][st0]) = p;
        f4v one = (f4v){1.f, 1.f, 1.f, 1.f};
        *(f4v*)(BL + (size_t)((TM1_ - 1) * N_ + n) * C_ + st0) = one;
      }
    }
    if (tid == 0) DD[(TM1_ - 1) * N_ + n] = 0.f;
    // 2-deep prefetch: eo_nx = eo(t+1) for first iter, eo_p1 for second
    float K_nx = Karr[n * T_ + TM1_];
    float K_p1 = Karr[n * T_ + TM1_ - 1];
    f4v eo_nx[2], eo_p1[2];
#pragma unroll
    for (int m = 0; m < 2; ++m) {
      eo_nx[m] = *(const f4v*)(EOBS + (size_t)(n * T_ + TM1_ - 1) * C_ + stb + (m << 4));
      eo_p1[m] = *(const f4v*)(EOBS + (size_t)(n * T_ + TM1_ - 2) * C_ + stb + (m << 4));
    }
    float invm = 1.f, logm = 0.f;
    __syncthreads();

#pragma unroll 1
    for (int it = 0, t = TM1_ - 2; t >= 0; --t, ++it) {
      const int cur = it & 1, nxt = cur ^ 1;
      f4v eo_p2[2];
      float K_p2 = 0.f;
      if (t >= 2) {
#pragma unroll
        for (int m = 0; m < 2; ++m)
          eo_p2[m] = *(const f4v*)(EOBS + (size_t)(n * T_ + t - 1) * C_ + stb + (m << 4));
        K_p2 = Karr[n * T_ + t];
      }
      h8_t bf[8];
#pragma unroll
      for (int kt = 0; kt < 8; ++kt)
        bf[kt] = *(const h8_t*)(&ubuf[cur][(kt << 5) + (quad << 3)]);
      f4v acc[2];
      acc[0] = (f4v){0.f, 0.f, 0.f, 0.f};
      acc[1] = (f4v){0.f, 0.f, 0.f, 0.f};
#pragma unroll
      for (int kt = 0; kt < 8; ++kt) {
        acc[0] = __builtin_amdgcn_mfma_f32_16x16x32_f16(afrag[0][kt], bf[kt], acc[0], 0, 0, 0);
        acc[1] = __builtin_amdgcn_mfma_f32_16x16x32_f16(afrag[1][kt], bf[kt], acc[1], 0, 0, 0);
      }
      Dacc += K_nx + logm;
      float lmx = -1e30f;
      f4v blv[2];
#pragma unroll
      for (int m = 0; m < 2; ++m) {
#pragma unroll
        for (int r = 0; r < 4; ++r) {
          float b = acc[m][r] * invm;
          blv[m][r] = b;
          float v = b * eo_nx[m][r];
          vval[m][r] = v;
          lmx = fmaxf(lmx, v);
        }
      }
      if (((it + 1) & 3) == 3) {
        float wmm = wave_red_max(lmx);
        if (lane == 0) red[w] = wmm;
      }
      if (nn16 == 0) {
#pragma unroll
        for (int m = 0; m < 2; ++m) {
          const int st0 = stb + (m << 4);
          h4_t p;
#pragma unroll
          for (int r = 0; r < 4; ++r) p[r] = (_Float16)vval[m][r];
          *(h4_t*)(&ubuf[nxt][st0]) = p;
          *(f4v*)(BL + (size_t)(t * N_ + n) * C_ + st0) = blv[m];
        }
      }
      if (tid == 0) DD[t * N_ + n] = Dacc;
      bar_lgkm();
      if (((it + 1) & 3) == 3) {
        f4v q0 = *(const f4v*)&red[0];
        f4v q1 = *(const f4v*)&red[4];
        float mm = fmaxf(fmaxf(fmaxf(q0[0], q0[1]), fmaxf(q0[2], q0[3])),
                         fmaxf(fmaxf(q1[0], q1[1]), fmaxf(q1[2], q1[3])));
        mm = fmaxf(mm, 1e-30f);
        invm = 1.f / mm;
        logm = __logf(mm);
      } else { invm = 1.f; logm = 0.f; }
#pragma unroll
      for (int m = 0; m < 2; ++m) { eo_nx[m] = eo_p1[m]; eo_p1[m] = eo_p2[m]; }
      K_nx = K_p1; K_p1 = K_p2;
    }
  }
}

// ---- elbo (+ fused evidence in block 0) ----
__global__ __launch_bounds__(256) void k_elbo(
    const float* __restrict__ Pf, const float* __restrict__ PLf,
    const float* __restrict__ PTf, const float* __restrict__ AL,
    const float* __restrict__ BL, const float* __restrict__ CC,
    const float* __restrict__ DD, const float* __restrict__ EOBS,
    const float* __restrict__ Karr, const float* __restrict__ LOGZ,
    float* __restrict__ out) {
  __shared__ __align__(16) float A_s[N_][C_];
  __shared__ __align__(16) float B_s[N_][C_];
  __shared__ float red[4];
  const int t = blockIdx.x;
  const int c = threadIdx.x;
  if (t == 0 && c == 0) {
    float s = 0.f;
#pragma unroll
    for (int nn = 0; nn < N_; ++nn) s += LOGZ[nn];
    out[1] = s;
  }
  float sc[N_], Kv[N_], cc[N_];
#pragma unroll
  for (int nn = 0; nn < N_; ++nn) {
    A_s[nn][c] = AL[(t * N_ + nn) * C_ + c];
    Kv[nn] = Karr[nn * T_ + t + 1];
    cc[nn] = CC[t * N_ + nn];
    sc[nn] = __expf(cc[nn] + DD[t * N_ + nn] + Kv[nn] - LOGZ[nn]);
  }
  __syncthreads();
  float accPA[N_], accPL[N_];
#pragma unroll
  for (int nn = 0; nn < N_; ++nn) { accPA[nn] = 0.f; accPL[nn] = 0.f; }
  const float4* pr = (const float4*)(Pf + c * C_);
  const float4* plr = (const float4*)(PLf + c * C_);
  for (int j = 0; j < C_ / 4; ++j) {
    float4 p = pr[j];
    float4 pl = plr[j];
#pragma unroll
    for (int nn = 0; nn < N_; ++nn) {
      float4 a = ((const float4*)A_s[nn])[j];
      accPA[nn] += p.x * a.x + p.y * a.y + p.z * a.z + p.w * a.w;
      accPL[nn] += pl.x * a.x + pl.y * a.y + pl.z * a.z + pl.w * a.w;
    }
  }
  float contrib = 0.f;
  float Bv[N_];
#pragma unroll
  for (int nn = 0; nn < N_; ++nn) {
    float eo = EOBS[(nn * T_ + t + 1) * C_ + c];
    float ob = __logf(eo) + Kv[nn];
    float B = eo * BL[(t * N_ + nn) * C_ + c] * sc[nn];
    Bv[nn] = B;
    contrib += B * fmaf(ob, accPA[nn], accPL[nn]);
  }
  if (t == 0) {
#pragma unroll
    for (int nn = 0; nn < N_; ++nn) B_s[nn][c] = Bv[nn];
    __syncthreads();
    const float4* ptq = (const float4*)(PTf + c * C_);
    float accPT[N_];
#pragma unroll
    for (int nn = 0; nn < N_; ++nn) accPT[nn] = 0.f;
    for (int j = 0; j < C_ / 4; ++j) {
      float4 p = ptq[j];
#pragma unroll
      for (int nn = 0; nn < N_; ++nn) {
        float4 b = ((const float4*)B_s[nn])[j];
        accPT[nn] += p.x * b.x + p.y * b.y + p.z * b.z + p.w * b.w;
      }
    }
#pragma unroll
    for (int nn = 0; nn < N_; ++nn) {
      float a0v = A_s[nn][c];
      if (a0v > 0.f)
        contrib += a0v * (__logf(a0v) + cc[nn]) * accPT[nn];
    }
  }
  contrib = wave_red_sum(contrib);
  if ((c & 63) == 0) red[c >> 6] = contrib;
  __syncthreads();
  if (c == 0) atomicAdd(out, (red[0] + red[1]) + (red[2] + red[3]));
}

extern "C" void kernel_launch(void* const* d_in, const int* in_sizes, int n_in,
                              void* d_out, int out_size, void* d_ws, size_t ws_size,
                              hipStream_t stream) {
  (void)in_sizes; (void)n_in; (void)out_size; (void)ws_size;
  const int* text = (const int*)d_in[0];
  const float* start_emb = (const float*)d_in[3];
  const float* state_emb = (const float*)d_in[4];
  const float* pre_emb   = (const float*)d_in[5];
  const float* sw1 = (const float*)d_in[6];  const float* sb1 = (const float*)d_in[7];
  const float* sw2 = (const float*)d_in[8];  const float* sb2 = (const float*)d_in[9];
  const float* sw3 = (const float*)d_in[10]; const float* sb3 = (const float*)d_in[11];
  const float* tw1 = (const float*)d_in[12]; const float* tb1 = (const float*)d_in[13];
  const float* tw2 = (const float*)d_in[14]; const float* tb2 = (const float*)d_in[15];
  const float* tw3 = (const float*)d_in[16]; const float* tb3 = (const float*)d_in[17];
  const float* ew1 = (const float*)d_in[18]; const float* eb1 = (const float*)d_in[19];
  const float* ew2 = (const float*)d_in[20]; const float* eb2 = (const float*)d_in[21];
  const float* ew3 = (const float*)d_in[22]; const float* eb3 = (const float*)d_in[23];
  float* out = (float*)d_out;

  char* p = (char*)d_ws;
  auto alloc = [&](size_t bytes) -> char* {
    char* r = p;
    p += (bytes + 255) & ~(size_t)255;
    return r;
  };
  float* slogit = (float*)alloc(C_ * 4);
  float* initv  = (float*)alloc(C_ * 4);
  float* denom  = (float*)alloc(C_ * 4);
  float* LOGZ   = (float*)alloc(N_ * 4);
  float* Pf     = (float*)alloc(C_ * C_ * 4);
  float* PLf    = (float*)alloc(C_ * C_ * 4);
  float* PTf    = (float*)alloc(C_ * C_ * 4);
  _Float16* P_h  = (_Float16*)alloc(C_ * C_ * 2);
  _Float16* PT_h = (_Float16*)alloc(C_ * C_ * 2);
  float* H2    = (float*)alloc(C_ * H_ * 4);
  float* H2T   = (float*)alloc(C_ * H_ * 4);
  float* partm = (float*)alloc(NB_ * C_ * 4);
  float* parts = (float*)alloc(NB_ * C_ * 4);
  float* EOBS  = (float*)alloc((size_t)N_ * T_ * C_ * 4);
  float* Karr  = (float*)alloc((size_t)N_ * T_ * 4);
  float* AL    = (float*)alloc((size_t)T_ * N_ * C_ * 4);
  float* BL    = (float*)alloc((size_t)TM1_ * N_ * C_ * 4);
  float* CC    = (float*)alloc((size_t)T_ * N_ * 4);
  float* DD    = (float*)alloc((size_t)TM1_ * N_ * 4);

  hipMemsetAsync(d_out, 0, 2 * sizeof(float), stream);

  k_start<<<dim3(C_ / 4), dim3(256), 0, stream>>>(start_emb, sw1, sb1, sw2, sb2, sw3, sb3, slogit);
  k_init<<<dim3(1), dim3(256), 0, stream>>>(slogit, initv);
  k_trans<<<dim3(C_ / 4), dim3(256), 0, stream>>>(state_emb, tw1, tb1, tw2, tb2, tw3, tb3,
                                                  Pf, PLf, PTf, P_h, PT_h);
  k_term_mlp<<<dim3(C_ / 4), dim3(256), 0, stream>>>(pre_emb, ew1, eb1, ew2, eb2, H2, H2T);
  k_term_stats<<<dim3(NB_), dim3(256), 0, stream>>>(H2, ew3, eb3, partm, parts);
  k_denom<<<dim3(1), dim3(256), 0, stream>>>(partm, parts, denom);
  k_obs2<<<dim3(N_ * T_ / 8), dim3(256), 0, stream>>>(text, H2T, ew3, eb3, denom, EOBS, Karr);
  k_scan5<<<dim3(2 * N_), dim3(512), 0, stream>>>(P_h, PT_h, initv, EOBS, Karr,
                                                  AL, BL, CC, DD, LOGZ);
  k_elbo<<<dim3(TM1_), dim3(256), 0, stream>>>(Pf, PLf, PTf, AL, BL, CC, DD,
                                               EOBS, Karr, LOGZ, out);
}

// Round 2
// 465.750 us; speedup vs baseline: 1.1818x; 1.1099x over previous
//
#include <hip/hip_runtime.h>
#include <hip/hip_bf16.h>

#define C_ 256
#define H_ 256
#define V_ 10000
#define N_ 8
#define T_ 256
#define TM1_ 255
#define NB_ ((V_ + 31) / 32)   // 313 col-tiles for the term head
#define SW_ 8                  // waves per scan block

typedef _Float16 h2_t __attribute__((ext_vector_type(2)));
typedef _Float16 h4_t __attribute__((ext_vector_type(4)));
typedef _Float16 h8_t __attribute__((ext_vector_type(8)));
typedef float f4v __attribute__((ext_vector_type(4)));

// barrier with LDS-only drain (global loads/stores stay in flight)
__device__ __forceinline__ void bar_lgkm() {
  asm volatile("s_waitcnt lgkmcnt(0)\ns_barrier" ::: "memory");
}

// ---- wave64 reductions via DPP (answer broadcast from lane 63) ----
__device__ __forceinline__ float wave_red_max(float v) {
#define DPP_MAX(ctrl) { int iv_ = __float_as_int(v); \
  int r_ = __builtin_amdgcn_update_dpp(iv_, iv_, ctrl, 0xF, 0xF, false); \
  v = fmaxf(v, __int_as_float(r_)); }
  DPP_MAX(0x111) DPP_MAX(0x112) DPP_MAX(0x114) DPP_MAX(0x118)
  DPP_MAX(0x142) DPP_MAX(0x143)
#undef DPP_MAX
  return __int_as_float(__builtin_amdgcn_readlane(__float_as_int(v), 63));
}
__device__ __forceinline__ float wave_red_sum(float v) {
#define DPP_ADD(ctrl) { \
  int r_ = __builtin_amdgcn_update_dpp(0, __float_as_int(v), ctrl, 0xF, 0xF, true); \
  v += __int_as_float(r_); }
  DPP_ADD(0x111) DPP_ADD(0x112) DPP_ADD(0x114) DPP_ADD(0x118)
  DPP_ADD(0x142) DPP_ADD(0x143)
#undef DPP_ADD
  return __int_as_float(__builtin_amdgcn_readlane(__float_as_int(v), 63));
}

__device__ __forceinline__ float block_allmax(float v, float* red) {
  v = wave_red_max(v);
  if ((threadIdx.x & 63) == 0) red[threadIdx.x >> 6] = v;
  __syncthreads();
  v = fmaxf(fmaxf(red[0], red[1]), fmaxf(red[2], red[3]));
  __syncthreads();
  return v;
}
__device__ __forceinline__ float block_allsum(float v, float* red) {
  v = wave_red_sum(v);
  if ((threadIdx.x & 63) == 0) red[threadIdx.x >> 6] = v;
  __syncthreads();
  v = (red[0] + red[1]) + (red[2] + red[3]);
  __syncthreads();
  return v;
}

// ---- residual MLP body: 4 rows per block, 256 threads ----
__device__ __forceinline__ void mlp4(
    const float* __restrict__ emb,
    const float* __restrict__ w1, const float* __restrict__ b1,
    const float* __restrict__ w2, const float* __restrict__ b2,
    int r0, float (&e_s)[4][C_], float (&h_s)[4][C_], float (&h2_s)[4][C_]) {
  const int tid = threadIdx.x;
#pragma unroll
  for (int rr = 0; rr < 4; ++rr)
    e_s[rr][tid] = emb[(r0 + rr) * H_ + tid];
  __syncthreads();
  float bb = b1[tid];
  float a0 = bb, a1 = bb, a2 = bb, a3 = bb;
  for (int k4 = 0; k4 < H_ / 4; ++k4) {
    float4 e0 = ((const float4*)e_s[0])[k4];
    float4 e1 = ((const float4*)e_s[1])[k4];
    float4 e2 = ((const float4*)e_s[2])[k4];
    float4 e3 = ((const float4*)e_s[3])[k4];
    const float* wp = w1 + (k4 * 4) * H_ + tid;
    float wa = wp[0], wb = wp[H_], wc = wp[2 * H_], wd = wp[3 * H_];
    a0 = fmaf(e0.x, wa, a0); a0 = fmaf(e0.y, wb, a0);
    a0 = fmaf(e0.z, wc, a0); a0 = fmaf(e0.w, wd, a0);
    a1 = fmaf(e1.x, wa, a1); a1 = fmaf(e1.y, wb, a1);
    a1 = fmaf(e1.z, wc, a1); a1 = fmaf(e1.w, wd, a1);
    a2 = fmaf(e2.x, wa, a2); a2 = fmaf(e2.y, wb, a2);
    a2 = fmaf(e2.z, wc, a2); a2 = fmaf(e2.w, wd, a2);
    a3 = fmaf(e3.x, wa, a3); a3 = fmaf(e3.y, wb, a3);
    a3 = fmaf(e3.z, wc, a3); a3 = fmaf(e3.w, wd, a3);
  }
  h_s[0][tid] = fmaxf(a0, 0.f);
  h_s[1][tid] = fmaxf(a1, 0.f);
  h_s[2][tid] = fmaxf(a2, 0.f);
  h_s[3][tid] = fmaxf(a3, 0.f);
  __syncthreads();
  bb = b2[tid];
  a0 = bb; a1 = bb; a2 = bb; a3 = bb;
  for (int k4 = 0; k4 < H_ / 4; ++k4) {
    float4 e0 = ((const float4*)h_s[0])[k4];
    float4 e1 = ((const float4*)h_s[1])[k4];
    float4 e2 = ((const float4*)h_s[2])[k4];
    float4 e3 = ((const float4*)h_s[3])[k4];
    const float* wp = w2 + (k4 * 4) * H_ + tid;
    float wa = wp[0], wb = wp[H_], wc = wp[2 * H_], wd = wp[3 * H_];
    a0 = fmaf(e0.x, wa, a0); a0 = fmaf(e0.y, wb, a0);
    a0 = fmaf(e0.z, wc, a0); a0 = fmaf(e0.w, wd, a0);
    a1 = fmaf(e1.x, wa, a1); a1 = fmaf(e1.y, wb, a1);
    a1 = fmaf(e1.z, wc, a1); a1 = fmaf(e1.w, wd, a1);
    a2 = fmaf(e2.x, wa, a2); a2 = fmaf(e2.y, wb, a2);
    a2 = fmaf(e2.z, wc, a2); a2 = fmaf(e2.w, wd, a2);
    a3 = fmaf(e3.x, wa, a3); a3 = fmaf(e3.y, wb, a3);
    a3 = fmaf(e3.z, wc, a3); a3 = fmaf(e3.w, wd, a3);
  }
  h2_s[0][tid] = fmaxf(a0, 0.f) + e_s[0][tid];
  h2_s[1][tid] = fmaxf(a1, 0.f) + e_s[1][tid];
  h2_s[2][tid] = fmaxf(a2, 0.f) + e_s[2][tid];
  h2_s[3][tid] = fmaxf(a3, 0.f) + e_s[3][tid];
  __syncthreads();
}

// ---- fused heads: blocks 0..63 start-MLP, 64..127 trans-MLP, 128..191 term-MLP
__global__ __launch_bounds__(256) void k_heads(
    // start
    const float* __restrict__ semb, const float* __restrict__ sw1,
    const float* __restrict__ sb1, const float* __restrict__ sw2,
    const float* __restrict__ sb2, const float* __restrict__ sw3,
    const float* __restrict__ sb3, float* __restrict__ slogit,
    // trans
    const float* __restrict__ temb, const float* __restrict__ tw1,
    const float* __restrict__ tb1, const float* __restrict__ tw2,
    const float* __restrict__ tb2, const float* __restrict__ tw3,
    const float* __restrict__ tb3, float* __restrict__ Pf,
    float* __restrict__ PLf, float* __restrict__ PTf,
    _Float16* __restrict__ P_h, _Float16* __restrict__ PT_h,
    // term
    const float* __restrict__ eemb, const float* __restrict__ ew1,
    const float* __restrict__ eb1, const float* __restrict__ ew2,
    const float* __restrict__ eb2, float* __restrict__ H2,
    float* __restrict__ H2T) {
  __shared__ __align__(16) float e_s[4][C_], h_s[4][C_], h2_s[4][C_];
  __shared__ float red[4];
  const int b = blockIdx.x;
  const int tid = threadIdx.x;
  if (b < 64) {
    const int r0 = b * 4;
    mlp4(semb, sw1, sb1, sw2, sb2, r0, e_s, h_s, h2_s);
    float w3v = sw3[tid];
    float s0 = block_allsum(h2_s[0][tid] * w3v, red);
    float s1 = block_allsum(h2_s[1][tid] * w3v, red);
    float s2 = block_allsum(h2_s[2][tid] * w3v, red);
    float s3 = block_allsum(h2_s[3][tid] * w3v, red);
    if (tid == 0) {
      float bb = sb3[0];
      slogit[r0 + 0] = s0 + bb;
      slogit[r0 + 1] = s1 + bb;
      slogit[r0 + 2] = s2 + bb;
      slogit[r0 + 3] = s3 + bb;
    }
  } else if (b < 128) {
    const int r0 = (b - 64) * 4;
    mlp4(temb, tw1, tb1, tw2, tb2, r0, e_s, h_s, h2_s);
    float lb = tb3[tid];
    float l0 = lb, l1 = lb, l2 = lb, l3 = lb;
    for (int k4 = 0; k4 < H_ / 4; ++k4) {
      float4 e0 = ((const float4*)h2_s[0])[k4];
      float4 e1 = ((const float4*)h2_s[1])[k4];
      float4 e2 = ((const float4*)h2_s[2])[k4];
      float4 e3 = ((const float4*)h2_s[3])[k4];
      const float* wp = tw3 + (k4 * 4) * C_ + tid;
      float wa = wp[0], wb = wp[C_], wc = wp[2 * C_], wd = wp[3 * C_];
      l0 = fmaf(e0.x, wa, l0); l0 = fmaf(e0.y, wb, l0);
      l0 = fmaf(e0.z, wc, l0); l0 = fmaf(e0.w, wd, l0);
      l1 = fmaf(e1.x, wa, l1); l1 = fmaf(e1.y, wb, l1);
      l1 = fmaf(e1.z, wc, l1); l1 = fmaf(e1.w, wd, l1);
      l2 = fmaf(e2.x, wa, l2); l2 = fmaf(e2.y, wb, l2);
      l2 = fmaf(e2.z, wc, l2); l2 = fmaf(e2.w, wd, l2);
      l3 = fmaf(e3.x, wa, l3); l3 = fmaf(e3.y, wb, l3);
      l3 = fmaf(e3.z, wc, l3); l3 = fmaf(e3.w, wd, l3);
    }
    float lg[4] = {l0, l1, l2, l3};
#pragma unroll
    for (int rr = 0; rr < 4; ++rr) {
      float m = block_allmax(lg[rr], red);
      float e = __expf(lg[rr] - m);
      float se = block_allsum(e, red);
      float p = e / se;                       // softmax prob
      float tv = lg[rr] - m - __logf(se);     // log-softmax
      const int r = r0 + rr;
      Pf[r * C_ + tid] = p;
      PLf[r * C_ + tid] = p * tv;
      PTf[tid * C_ + r] = p;
      P_h[r * C_ + tid] = (_Float16)p;
      PT_h[tid * C_ + r] = (_Float16)p;
    }
  } else {
    const int r0 = (b - 128) * 4;
    mlp4(eemb, ew1, eb1, ew2, eb2, r0, e_s, h_s, h2_s);
#pragma unroll
    for (int rr = 0; rr < 4; ++rr) {
      const int r = r0 + rr;
      float v = h2_s[rr][tid];
      H2[r * H_ + tid] = v;
      H2T[tid * C_ + r] = v;
    }
  }
}

// ---- term head: per-row online logsumexp partials over a 32-col tile ----
__global__ __launch_bounds__(256) void k_term_stats(
    const float* __restrict__ H2, const float* __restrict__ w3,
    const float* __restrict__ b3, float* __restrict__ partm,
    float* __restrict__ parts) {
  __shared__ __align__(16) float w3_s[H_][32];
  __shared__ float b3_s[32];
  const int v0 = blockIdx.x * 32;
  const int tid = threadIdx.x;
  const int ncols = min(32, V_ - v0);
  for (int idx = tid; idx < H_ * 32; idx += 256) {
    int k = idx >> 5, c = idx & 31;
    w3_s[k][c] = (c < ncols) ? w3[k * V_ + v0 + c] : 0.f;
  }
  if (tid < 32) b3_s[tid] = (tid < ncols) ? b3[v0 + tid] : 0.f;
  __syncthreads();
  float acc[32];
#pragma unroll
  for (int c = 0; c < 32; ++c) acc[c] = 0.f;
  const float4* hq = (const float4*)(H2 + tid * H_);
  for (int k4 = 0; k4 < H_ / 4; ++k4) {
    float4 h = hq[k4];
    float hk[4];
    *(float4*)hk = h;
#pragma unroll
    for (int kk = 0; kk < 4; ++kk) {
      float hv = hk[kk];
      const int k = k4 * 4 + kk;
      const float4* wq = (const float4*)(&w3_s[k][0]);
#pragma unroll
      for (int c4 = 0; c4 < 8; ++c4) {
        float4 w = wq[c4];
        acc[c4 * 4 + 0] = fmaf(hv, w.x, acc[c4 * 4 + 0]);
        acc[c4 * 4 + 1] = fmaf(hv, w.y, acc[c4 * 4 + 1]);
        acc[c4 * 4 + 2] = fmaf(hv, w.z, acc[c4 * 4 + 2]);
        acc[c4 * 4 + 3] = fmaf(hv, w.w, acc[c4 * 4 + 3]);
      }
    }
  }
  float m = -1e30f;
#pragma unroll
  for (int c = 0; c < 32; ++c) {
    acc[c] += b3_s[c];
    if (c < ncols) m = fmaxf(m, acc[c]);
  }
  float se = 0.f;
#pragma unroll
  for (int c = 0; c < 32; ++c)
    if (c < ncols) se += __expf(acc[c] - m);
  partm[blockIdx.x * C_ + tid] = m;
  parts[blockIdx.x * C_ + tid] = se;
}

// ---- small fused: block 0 = init log-softmax, block 1 = term denom ----
__global__ void k_small(const float* __restrict__ slogit,
                        float* __restrict__ initv,
                        const float* __restrict__ partm,
                        const float* __restrict__ parts,
                        float* __restrict__ denom) {
  __shared__ float red[4];
  const int tid = threadIdx.x;
  if (blockIdx.x == 0) {
    float x = slogit[tid];
    float m = block_allmax(x, red);
    float se = block_allsum(__expf(x - m), red);
    initv[tid] = x - m - __logf(se);
  } else {
    const int r = tid;
    float m = -1e30f;
    for (int b = 0; b < NB_; ++b) m = fmaxf(m, partm[b * C_ + r]);
    float s = 0.f;
    for (int b = 0; b < NB_; ++b)
      s += parts[b * C_ + r] * __expf(partm[b * C_ + r] - m);
    denom[r] = m + __logf(s);
  }
}

// ---- emissions: EOBS[nt][c] = exp(obs - K), Karr[nt] = max_c obs ----
__global__ __launch_bounds__(256) void k_obs2(
    const int* __restrict__ text, const float* __restrict__ H2T,
    const float* __restrict__ w3, const float* __restrict__ b3,
    const float* __restrict__ denom, float* __restrict__ EOBS,
    float* __restrict__ Karr) {
  __shared__ __align__(16) float w_s[H_][8];   // [k][i]
  __shared__ float redm[4][8];
  const int c = threadIdx.x;
  const int wid = c >> 6;
  const int lane = c & 63;
  const int base = blockIdx.x * 8;
  int tok[8];
#pragma unroll
  for (int i = 0; i < 8; ++i) tok[i] = text[base + i];
  float wtmp[8];
#pragma unroll
  for (int i = 0; i < 8; ++i) wtmp[i] = w3[c * V_ + tok[i]];
  float b3t[8];
#pragma unroll
  for (int i = 0; i < 8; ++i) b3t[i] = b3[tok[i]];
#pragma unroll
  for (int i = 0; i < 8; ++i) w_s[c][i] = wtmp[i];
  __syncthreads();
  float acc[8];
#pragma unroll
  for (int i = 0; i < 8; ++i) acc[i] = 0.f;
  for (int k4 = 0; k4 < H_ / 4; ++k4) {
    float hv[4];
#pragma unroll
    for (int kk = 0; kk < 4; ++kk) hv[kk] = H2T[(k4 * 4 + kk) * C_ + c];
#pragma unroll
    for (int kk = 0; kk < 4; ++kk) {
      const float4* wq = (const float4*)(&w_s[k4 * 4 + kk][0]);
      float4 wa = wq[0], wb = wq[1];
      acc[0] = fmaf(hv[kk], wa.x, acc[0]);
      acc[1] = fmaf(hv[kk], wa.y, acc[1]);
      acc[2] = fmaf(hv[kk], wa.z, acc[2]);
      acc[3] = fmaf(hv[kk], wa.w, acc[3]);
      acc[4] = fmaf(hv[kk], wb.x, acc[4]);
      acc[5] = fmaf(hv[kk], wb.y, acc[5]);
      acc[6] = fmaf(hv[kk], wb.z, acc[6]);
      acc[7] = fmaf(hv[kk], wb.w, acc[7]);
    }
  }
  float dn = denom[c];
  float obsv[8];
#pragma unroll
  for (int i = 0; i < 8; ++i) obsv[i] = acc[i] + b3t[i] - dn;
#pragma unroll
  for (int i = 0; i < 8; ++i) {
    float wm = wave_red_max(obsv[i]);
    if (lane == 0) redm[wid][i] = wm;
  }
  __syncthreads();
#pragma unroll
  for (int i = 0; i < 8; ++i) {
    float Ki = fmaxf(fmaxf(redm[0][i], redm[1][i]),
                     fmaxf(redm[2][i], redm[3][i]));
    EOBS[(base + i) * C_ + c] = __expf(obsv[i] - Ki);
    if (c == 0) Karr[base + i] = Ki;
  }
}

// ---- MFMA scan v6 ----
// Same per-element arithmetic as k_scan5; two structural latency fixes:
// 1. eo prefetch via slot-rotated unroll-3 (load eo(t+3)->slot[t%3], consume
//    slot[(t+1)%3]): static registers, no shift-copies -> genuine 2-body
//    window for the L2/L3 latency (the v5 register shift forced a vmcnt wait
//    at the END of the SAME iteration the load was issued).
// 2. Karr eliminated from the hot loop: CC/DD now carry only sum(log m)
//    (CL/DL); the K prefix/suffix parts telescope in k_elbo's sc exponent to
//    a single per-sequence constant KPtot (computed once in the prologue,
//    passed via KT). This removes a uniform s_load whose latency was drained
//    by every iteration's lgkmcnt(0) barrier.
__global__ __launch_bounds__(512, 2) void k_scan6(
    const _Float16* __restrict__ P_h, const _Float16* __restrict__ PT_h,
    const float* __restrict__ initv, const float* __restrict__ EOBS,
    const float* __restrict__ Karr, float* __restrict__ AL,
    float* __restrict__ BL, float* __restrict__ CC, float* __restrict__ DD,
    float* __restrict__ KT, float* __restrict__ LOGZ) {
  __shared__ __align__(16) _Float16 ubuf[2][C_];
  __shared__ __align__(16) float red[SW_];
  const int tid = threadIdx.x;
  const int w = tid >> 6;
  const int lane = tid & 63;
  const int quad = lane >> 4;        // k-group within fragment
  const int nn16 = lane & 15;        // replicated column index
  const bool bwd = blockIdx.x >= N_;
  const int n = blockIdx.x & (N_ - 1);
  const _Float16* __restrict__ M = bwd ? PT_h : P_h;

  // A fragments: A[row = w*32 + m*16 + nn16][k = kt*32 + quad*8 + j]
  h8_t afrag[2][8];
#pragma unroll
  for (int m = 0; m < 2; ++m) {
    const _Float16* rp = M + (size_t)((w << 5) + (m << 4) + nn16) * C_ + (quad << 3);
#pragma unroll
    for (int kt = 0; kt < 8; ++kt)
      afrag[m][kt] = *(const h8_t*)(rp + (kt << 5));
  }
  const int stb = (w << 5) + (quad << 2);
  const float* __restrict__ eob = EOBS + (size_t)n * T_ * C_;
  int cur = 0;

  f4v eoA[2], eoB[2], eoC[2];
#define FLOAD(SL, tt) { \
  eo##SL[0] = *(const f4v*)(eob + (size_t)(tt) * C_ + stb); \
  eo##SL[1] = *(const f4v*)(eob + (size_t)(tt) * C_ + stb + 16); }

  if (!bwd) {
    // ---- prologue: KPtot = sum_{s=1..255} K(s) (K parts hoisted out of loop)
    float kvp = (tid >= 1 && tid < 256) ? Karr[n * T_ + tid] : 0.f;
    kvp = wave_red_sum(kvp);
    if (lane == 0) red[w] = kvp;
    __syncthreads();
    float KPtot = ((red[0] + red[1]) + (red[2] + red[3])) +
                  ((red[4] + red[5]) + (red[6] + red[7]));
    if (tid == 0) KT[n] = KPtot;
    __syncthreads();

    // ---- init: x0 = initv + log(eo0) + K0 ; u0 = exp(x0 - m0) ----
    float K0 = Karr[n * T_];
    f4v x0[2];
    float lmax = -1e30f;
#pragma unroll
    for (int m = 0; m < 2; ++m) {
      const int st0 = stb + (m << 4);
      f4v iv = *(const f4v*)(initv + st0);
      f4v e0 = *(const f4v*)(eob + st0);
#pragma unroll
      for (int r = 0; r < 4; ++r) {
        x0[m][r] = iv[r] + __logf(e0[r]) + K0;
        lmax = fmaxf(lmax, x0[m][r]);
      }
    }
    float wmx = wave_red_max(lmax);
    if (lane == 0) red[w] = wmx;
    __syncthreads();
    f4v rr0 = *(const f4v*)&red[0];
    f4v rr1 = *(const f4v*)&red[4];
    float m0 = fmaxf(fmaxf(fmaxf(rr0[0], rr0[1]), fmaxf(rr0[2], rr0[3])),
                     fmaxf(fmaxf(rr1[0], rr1[1]), fmaxf(rr1[2], rr1[3])));
    __syncthreads();
    float CLacc = m0;            // = m0 + sum(log m); K-part lives in KT
    f4v uval[2];
#pragma unroll
    for (int m = 0; m < 2; ++m) {
      const int st0 = stb + (m << 4);
#pragma unroll
      for (int r = 0; r < 4; ++r) uval[m][r] = __expf(x0[m][r] - m0);
      if (nn16 == 0) {
        h4_t p;
#pragma unroll
        for (int r = 0; r < 4; ++r) p[r] = (_Float16)uval[m][r];
        *(h4_t*)(&ubuf[0][st0]) = p;
        *(f4v*)(AL + (size_t)(0 * N_ + n) * C_ + st0) = uval[m];
      }
    }
    if (tid == 0) CC[0 * N_ + n] = CLacc;
    float invm = 1.f, logm = 0.f;
    FLOAD(B, 1)
    FLOAD(C, 2)
    __syncthreads();

#define FSTEP(tt, SL, SC) do { \
    if ((tt) + 3 < T_) FLOAD(SL, (tt) + 3) \
    const _Float16* ubc = &ubuf[cur][0]; \
    _Float16* ubn = &ubuf[cur ^ 1][0]; \
    h8_t bf[8]; \
    _Pragma("unroll") for (int kt = 0; kt < 8; ++kt) \
      bf[kt] = *(const h8_t*)(ubc + (kt << 5) + (quad << 3)); \
    f4v acc0 = (f4v){0.f, 0.f, 0.f, 0.f}; \
    f4v acc1 = (f4v){0.f, 0.f, 0.f, 0.f}; \
    _Pragma("unroll") for (int kt = 0; kt < 8; ++kt) { \
      acc0 = __builtin_amdgcn_mfma_f32_16x16x32_f16(afrag[0][kt], bf[kt], acc0, 0, 0, 0); \
      acc1 = __builtin_amdgcn_mfma_f32_16x16x32_f16(afrag[1][kt], bf[kt], acc1, 0, 0, 0); } \
    float lmx = -1e30f; \
    _Pragma("unroll") for (int r = 0; r < 4; ++r) { \
      uval[0][r] = acc0[r] * invm * eo##SC[0][r]; lmx = fmaxf(lmx, uval[0][r]); \
      uval[1][r] = acc1[r] * invm * eo##SC[1][r]; lmx = fmaxf(lmx, uval[1][r]); } \
    CLacc += logm; \
    const bool resc_ = ((tt) & 3) == 3; \
    if (resc_) { \
      float wmm = wave_red_max(lmx); \
      if (lane == 0) red[w] = wmm; } \
    if (nn16 == 0) { \
      _Pragma("unroll") for (int m = 0; m < 2; ++m) { \
        const int st0 = stb + (m << 4); \
        h4_t p; \
        _Pragma("unroll") for (int r = 0; r < 4; ++r) p[r] = (_Float16)uval[m][r]; \
        *(h4_t*)(ubn + st0) = p; \
        *(f4v*)(AL + (size_t)(((tt) + 1) * N_ + n) * C_ + st0) = uval[m]; } } \
    if (tid == 0) CC[((tt) + 1) * N_ + n] = CLacc; \
    bar_lgkm(); \
    if (resc_) { \
      f4v q0 = *(const f4v*)&red[0]; \
      f4v q1 = *(const f4v*)&red[4]; \
      float mm = fmaxf(fmaxf(fmaxf(q0[0], q0[1]), fmaxf(q0[2], q0[3])), \
                       fmaxf(fmaxf(q1[0], q1[1]), fmaxf(q1[2], q1[3]))); \
      mm = fmaxf(mm, 1e-30f); \
      invm = 1.f / mm; \
      logm = __logf(mm); \
    } else { invm = 1.f; logm = 0.f; } \
    cur ^= 1; \
  } while (0)

#pragma unroll 1
    for (int tb = 0; tb < TM1_; tb += 3) {   // 255 = 3*85
      FSTEP(tb + 0, A, B);
      FSTEP(tb + 1, B, C);
      FSTEP(tb + 2, C, A);
    }
#undef FSTEP
    // logZ = log(sum of last u / 16 replicas) + CL + KPtot
    float s = 0.f;
#pragma unroll
    for (int m = 0; m < 2; ++m)
      s += (uval[m][0] + uval[m][1]) + (uval[m][2] + uval[m][3]);
    s = wave_red_sum(s);
    if (lane == 0) red[w] = s;
    __syncthreads();
    if (tid == 0) {
      float S = ((red[0] + red[1]) + (red[2] + red[3])) +
                ((red[4] + red[5]) + (red[6] + red[7]));
      LOGZ[n] = __logf(S * (1.f / 16.f)) + CLacc + KPtot;
    }
  } else {
    // ---- bwd: v = bl*eo staged; bl' = (PT*v)*invm; DL = sum(log m) only ----
    float DLacc = 0.f;
    f4v vval[2];
#pragma unroll
    for (int m = 0; m < 2; ++m) {
      const int st0 = stb + (m << 4);
      vval[m] = *(const f4v*)(eob + (size_t)TM1_ * C_ + st0);
      if (nn16 == 0) {
        h4_t p;
#pragma unroll
        for (int r = 0; r < 4; ++r) p[r] = (_Float16)vval[m][r];
        *(h4_t*)(&ubuf[0][st0]) = p;
        f4v one = (f4v){1.f, 1.f, 1.f, 1.f};
        *(f4v*)(BL + (size_t)((TM1_ - 1) * N_ + n) * C_ + st0) = one;
      }
    }
    if (tid == 0) DD[(TM1_ - 1) * N_ + n] = 0.f;
    FLOAD(B, TM1_ - 1)   // eo(254), consumed at it=0
    FLOAD(C, TM1_ - 2)   // eo(253), consumed at it=1
    __syncthreads();

#define BSTEP(itv, SL, SC) do { \
    if ((itv) < TM1_ - 1) { \
      const int t_ = TM1_ - 2 - (itv); \
      if ((itv) <= TM1_ - 4) FLOAD(SL, t_ - 1) \
      float invm = 1.f, logm = 0.f; \
      if (((itv) & 3) == 3) { \
        f4v q0 = *(const f4v*)&red[0]; \
        f4v q1 = *(const f4v*)&red[4]; \
        float mm = fmaxf(fmaxf(fmaxf(q0[0], q0[1]), fmaxf(q0[2], q0[3])), \
                         fmaxf(fmaxf(q1[0], q1[1]), fmaxf(q1[2], q1[3]))); \
        mm = fmaxf(mm, 1e-30f); \
        invm = 1.f / mm; \
        logm = __logf(mm); } \
      const _Float16* ubc = &ubuf[cur][0]; \
      _Float16* ubn = &ubuf[cur ^ 1][0]; \
      h8_t bf[8]; \
      _Pragma("unroll") for (int kt = 0; kt < 8; ++kt) \
        bf[kt] = *(const h8_t*)(ubc + (kt << 5) + (quad << 3)); \
      f4v acc0 = (f4v){0.f, 0.f, 0.f, 0.f}; \
      f4v acc1 = (f4v){0.f, 0.f, 0.f, 0.f}; \
      _Pragma("unroll") for (int kt = 0; kt < 8; ++kt) { \
        acc0 = __builtin_amdgcn_mfma_f32_16x16x32_f16(afrag[0][kt], bf[kt], acc0, 0, 0, 0); \
        acc1 = __builtin_amdgcn_mfma_f32_16x16x32_f16(afrag[1][kt], bf[kt], acc1, 0, 0, 0); } \
      DLacc += logm; \
      float lmx = -1e30f; \
      f4v blv[2]; \
      _Pragma("unroll") for (int r = 0; r < 4; ++r) { \
        blv[0][r] = acc0[r] * invm; \
        vval[0][r] = blv[0][r] * eo##SC[0][r]; lmx = fmaxf(lmx, vval[0][r]); \
        blv[1][r] = acc1[r] * invm; \
        vval[1][r] = blv[1][r] * eo##SC[1][r]; lmx = fmaxf(lmx, vval[1][r]); } \
      if ((((itv) + 1) & 3) == 3) { \
        float wmm = wave_red_max(lmx); \
        if (lane == 0) red[w] = wmm; } \
      if (nn16 == 0) { \
        _Pragma("unroll") for (int m = 0; m < 2; ++m) { \
          const int st0 = stb + (m << 4); \
          h4_t p; \
          _Pragma("unroll") for (int r = 0; r < 4; ++r) p[r] = (_Float16)vval[m][r]; \
          *(h4_t*)(ubn + st0) = p; \
          *(f4v*)(BL + (size_t)(t_ * N_ + n) * C_ + st0) = blv[m]; } } \
      if (tid == 0) DD[t_ * N_ + n] = DLacc; \
      bar_lgkm(); \
      cur ^= 1; \
    } \
  } while (0)

#pragma unroll 1
    for (int ib = 0; ib < 255; ib += 3) {   // it = 0..253 live, 254 guarded off
      BSTEP(ib + 0, A, B);
      BSTEP(ib + 1, B, C);
      BSTEP(ib + 2, C, A);
    }
#undef BSTEP
  }
#undef FLOAD
}

// ---- elbo (+ fused evidence in block 0) ----
// sc exponent: CC/DD now carry only sum(log m); the K prefix+suffix+K(t+1)
// telescope to the per-sequence constant KT[nn].
__global__ __launch_bounds__(256) void k_elbo(
    const float* __restrict__ Pf, const float* __restrict__ PLf,
    const float* __restrict__ PTf, const float* __restrict__ AL,
    const float* __restrict__ BL, const float* __restrict__ CC,
    const float* __restrict__ DD, const float* __restrict__ EOBS,
    const float* __restrict__ Karr, const float* __restrict__ KT,
    const float* __restrict__ LOGZ, float* __restrict__ out) {
  __shared__ __align__(16) float A_s[N_][C_];
  __shared__ __align__(16) float B_s[N_][C_];
  __shared__ float red[4];
  const int t = blockIdx.x;
  const int c = threadIdx.x;
  if (t == 0 && c == 0) {
    float s = 0.f;
#pragma unroll
    for (int nn = 0; nn < N_; ++nn) s += LOGZ[nn];
    out[1] = s;
  }
  float sc[N_], Kv[N_], cc[N_];
#pragma unroll
  for (int nn = 0; nn < N_; ++nn) {
    A_s[nn][c] = AL[(t * N_ + nn) * C_ + c];
    Kv[nn] = Karr[nn * T_ + t + 1];
    cc[nn] = CC[t * N_ + nn];
    sc[nn] = __expf(cc[nn] + DD[t * N_ + nn] + KT[nn] - LOGZ[nn]);
  }
  __syncthreads();
  float accPA[N_], accPL[N_];
#pragma unroll
  for (int nn = 0; nn < N_; ++nn) { accPA[nn] = 0.f; accPL[nn] = 0.f; }
  const float4* pr = (const float4*)(Pf + c * C_);
  const float4* plr = (const float4*)(PLf + c * C_);
  for (int j = 0; j < C_ / 4; ++j) {
    float4 p = pr[j];
    float4 pl = plr[j];
#pragma unroll
    for (int nn = 0; nn < N_; ++nn) {
      float4 a = ((const float4*)A_s[nn])[j];
      accPA[nn] += p.x * a.x + p.y * a.y + p.z * a.z + p.w * a.w;
      accPL[nn] += pl.x * a.x + pl.y * a.y + pl.z * a.z + pl.w * a.w;
    }
  }
  float contrib = 0.f;
  float Bv[N_];
#pragma unroll
  for (int nn = 0; nn < N_; ++nn) {
    float eo = EOBS[(nn * T_ + t + 1) * C_ + c];
    float ob = __logf(eo) + Kv[nn];
    float B = eo * BL[(t * N_ + nn) * C_ + c] * sc[nn];
    Bv[nn] = B;
    contrib += B * fmaf(ob, accPA[nn], accPL[nn]);
  }
  if (t == 0) {
#pragma unroll
    for (int nn = 0; nn < N_; ++nn) B_s[nn][c] = Bv[nn];
    __syncthreads();
    const float4* ptq = (const float4*)(PTf + c * C_);
    float accPT[N_];
#pragma unroll
    for (int nn = 0; nn < N_; ++nn) accPT[nn] = 0.f;
    for (int j = 0; j < C_ / 4; ++j) {
      float4 p = ptq[j];
#pragma unroll
      for (int nn = 0; nn < N_; ++nn) {
        float4 b = ((const float4*)B_s[nn])[j];
        accPT[nn] += p.x * b.x + p.y * b.y + p.z * b.z + p.w * b.w;
      }
    }
#pragma unroll
    for (int nn = 0; nn < N_; ++nn) {
      float a0v = A_s[nn][c];
      if (a0v > 0.f)
        contrib += a0v * (__logf(a0v) + cc[nn]) * accPT[nn];
    }
  }
  contrib = wave_red_sum(contrib);
  if ((c & 63) == 0) red[c >> 6] = contrib;
  __syncthreads();
  if (c == 0) atomicAdd(out, (red[0] + red[1]) + (red[2] + red[3]));
}

extern "C" void kernel_launch(void* const* d_in, const int* in_sizes, int n_in,
                              void* d_out, int out_size, void* d_ws, size_t ws_size,
                              hipStream_t stream) {
  (void)in_sizes; (void)n_in; (void)out_size; (void)ws_size;
  const int* text = (const int*)d_in[0];
  const float* start_emb = (const float*)d_in[3];
  const float* state_emb = (const float*)d_in[4];
  const float* pre_emb   = (const float*)d_in[5];
  const float* sw1 = (const float*)d_in[6];  const float* sb1 = (const float*)d_in[7];
  const float* sw2 = (const float*)d_in[8];  const float* sb2 = (const float*)d_in[9];
  const float* sw3 = (const float*)d_in[10]; const float* sb3 = (const float*)d_in[11];
  const float* tw1 = (const float*)d_in[12]; const float* tb1 = (const float*)d_in[13];
  const float* tw2 = (const float*)d_in[14]; const float* tb2 = (const float*)d_in[15];
  const float* tw3 = (const float*)d_in[16]; const float* tb3 = (const float*)d_in[17];
  const float* ew1 = (const float*)d_in[18]; const float* eb1 = (const float*)d_in[19];
  const float* ew2 = (const float*)d_in[20]; const float* eb2 = (const float*)d_in[21];
  const float* ew3 = (const float*)d_in[22]; const float* eb3 = (const float*)d_in[23];
  float* out = (float*)d_out;

  char* p = (char*)d_ws;
  auto alloc = [&](size_t bytes) -> char* {
    char* r = p;
    p += (bytes + 255) & ~(size_t)255;
    return r;
  };
  float* slogit = (float*)alloc(C_ * 4);
  float* initv  = (float*)alloc(C_ * 4);
  float* denom  = (float*)alloc(C_ * 4);
  float* LOGZ   = (float*)alloc(N_ * 4);
  float* KT     = (float*)alloc(N_ * 4);
  float* Pf     = (float*)alloc(C_ * C_ * 4);
  float* PLf    = (float*)alloc(C_ * C_ * 4);
  float* PTf    = (float*)alloc(C_ * C_ * 4);
  _Float16* P_h  = (_Float16*)alloc(C_ * C_ * 2);
  _Float16* PT_h = (_Float16*)alloc(C_ * C_ * 2);
  float* H2    = (float*)alloc(C_ * H_ * 4);
  float* H2T   = (float*)alloc(C_ * H_ * 4);
  float* partm = (float*)alloc(NB_ * C_ * 4);
  float* parts = (float*)alloc(NB_ * C_ * 4);
  float* EOBS  = (float*)alloc((size_t)N_ * T_ * C_ * 4);
  float* Karr  = (float*)alloc((size_t)N_ * T_ * 4);
  float* AL    = (float*)alloc((size_t)T_ * N_ * C_ * 4);
  float* BL    = (float*)alloc((size_t)TM1_ * N_ * C_ * 4);
  float* CC    = (float*)alloc((size_t)T_ * N_ * 4);
  float* DD    = (float*)alloc((size_t)TM1_ * N_ * 4);

  hipMemsetAsync(d_out, 0, 2 * sizeof(float), stream);

  k_heads<<<dim3(192), dim3(256), 0, stream>>>(
      start_emb, sw1, sb1, sw2, sb2, sw3, sb3, slogit,
      state_emb, tw1, tb1, tw2, tb2, tw3, tb3, Pf, PLf, PTf, P_h, PT_h,
      pre_emb, ew1, eb1, ew2, eb2, H2, H2T);
  k_term_stats<<<dim3(NB_), dim3(256), 0, stream>>>(H2, ew3, eb3, partm, parts);
  k_small<<<dim3(2), dim3(256), 0, stream>>>(slogit, initv, partm, parts, denom);
  k_obs2<<<dim3(N_ * T_ / 8), dim3(256), 0, stream>>>(text, H2T, ew3, eb3, denom, EOBS, Karr);
  k_scan6<<<dim3(2 * N_), dim3(512), 0, stream>>>(P_h, PT_h, initv, EOBS, Karr,
                                                  AL, BL, CC, DD, KT, LOGZ);
  k_elbo<<<dim3(TM1_), dim3(256), 0, stream>>>(Pf, PLf, PTf, AL, BL, CC, DD,
                                               EOBS, Karr, KT, LOGZ, out);
}